// Round 1
// baseline (731.107 us; speedup 1.0000x reference)
//
#include <hip/hip_runtime.h>

#define NG 16384
#define NT 200
#define NM 2
#define NS 8
#define FREEZE_EPS 3e-5f

// packed upper-triangular index, valid for i <= j
__device__ __forceinline__ constexpr int TRI(int i, int j) {
  return i * NS - (i * (i + 1)) / 2 + j;
}

__global__ __launch_bounds__(64, 1)
void kf_kernel(const float* __restrict__ x,
               const float* __restrict__ m0,
               const float* __restrict__ P0,
               const float* __restrict__ Fm,
               const float* __restrict__ Qm,
               const float* __restrict__ Hm,
               const float* __restrict__ Rm,
               float* __restrict__ out) {
  const int g = blockIdx.x * 64 + threadIdx.x;
  if (g >= NG) return;

  // --- load per-group state ---
  float m[NS];
#pragma unroll
  for (int i = 0; i < NS; ++i) m[i] = m0[(size_t)g * NS + i];

  float P[36];  // packed symmetric predicted covariance
#pragma unroll
  for (int i = 0; i < NS; ++i)
#pragma unroll
    for (int j = i; j < NS; ++j)
      P[TRI(i, j)] = P0[(size_t)g * NS * NS + i * NS + j];

  const float* xg = x + (size_t)g * NT * NM;
  float* mo = out + (size_t)g * NT * NM;                                  // means [G,T,M]
  float* co = out + (size_t)NG * NT * NM + (size_t)g * NT * NM * NM;      // covs  [G,T,M,M]

  float Kt0[NS], Kt1[NS];
#pragma unroll
  for (int i = 0; i < NS; ++i) { Kt0[i] = 0.f; Kt1[i] = 0.f; }
  float s00 = 0.f, s01 = 0.f, s11 = 0.f;
  bool frozen = false;

#pragma unroll 1
  for (int t = 0; t < NT; ++t) {
    // ---- measurement prediction: mm = H m ----
    float mm0 = 0.f, mm1 = 0.f;
#pragma unroll
    for (int s = 0; s < NS; ++s) {
      mm0 = fmaf(Hm[s], m[s], mm0);
      mm1 = fmaf(Hm[NS + s], m[s], mm1);
    }

    float HP0[NS], HP1[NS];
    if (!frozen) {
      // HP = H P
#pragma unroll
      for (int j = 0; j < NS; ++j) {
        float a0 = 0.f, a1 = 0.f;
#pragma unroll
        for (int s = 0; s < NS; ++s) {
          float Ps = (s <= j) ? P[TRI(s, j)] : P[TRI(j, s)];
          a0 = fmaf(Hm[s], Ps, a0);
          a1 = fmaf(Hm[NS + s], Ps, a1);
        }
        HP0[j] = a0; HP1[j] = a1;
      }
      // S = HP H^T + R (symmetric 2x2)
      s00 = Rm[0]; s01 = Rm[1]; s11 = Rm[3];
#pragma unroll
      for (int j = 0; j < NS; ++j) {
        s00 = fmaf(HP0[j], Hm[j],      s00);
        s01 = fmaf(HP0[j], Hm[NS + j], s01);
        s11 = fmaf(HP1[j], Hm[NS + j], s11);
      }
      // 2x2 inverse
      float det  = fmaf(s00, s11, -(s01 * s01));
      float rdet = 1.0f / det;
      float i00 = s11 * rdet, i01 = -s01 * rdet, i11 = s00 * rdet;
      // Kt = S^{-1} HP   [M,S]
#pragma unroll
      for (int j = 0; j < NS; ++j) {
        Kt0[j] = i00 * HP0[j] + i01 * HP1[j];
        Kt1[j] = i01 * HP0[j] + i11 * HP1[j];
      }
    }

    // ---- outputs for this step (pre-update) ----
    *reinterpret_cast<float2*>(mo + t * NM) = make_float2(mm0, mm1);
    *reinterpret_cast<float4*>(co + t * NM * NM) = make_float4(s00, s01, s01, s11);

    // ---- measurement update of mean ----
    float2 xt = *reinterpret_cast<const float2*>(xg + t * NM);
    float y0 = xt.x - mm0, y1 = xt.y - mm1;
    float mu_[NS];
#pragma unroll
    for (int s = 0; s < NS; ++s)
      mu_[s] = m[s] + Kt0[s] * y0 + Kt1[s] * y1;

    if (!frozen) {
      // P_u = P - Kt^T HP   (symmetric, packed, P preserved)
      float Pu[36];
#pragma unroll
      for (int i = 0; i < NS; ++i)
#pragma unroll
        for (int j = i; j < NS; ++j)
          Pu[TRI(i, j)] = P[TRI(i, j)] - (Kt0[i] * HP0[j] + Kt1[i] * HP1[j]);

      // P_n = F P_u F^T + Q  (upper triangle only)
      float Pn[36];
#pragma unroll
      for (int j = 0; j < NS; ++j) {
        float v[NS];  // v[k] = sum_l Pu[k][l] * F[j][l]
#pragma unroll
        for (int kk = 0; kk < NS; ++kk) {
          float acc = 0.f;
#pragma unroll
          for (int l = 0; l < NS; ++l) {
            float Pul = (kk <= l) ? Pu[TRI(kk, l)] : Pu[TRI(l, kk)];
            acc = fmaf(Pul, Fm[j * NS + l], acc);
          }
          v[kk] = acc;
        }
#pragma unroll
        for (int i = 0; i <= j; ++i) {
          float acc = Qm[i * NS + j];
#pragma unroll
          for (int kk = 0; kk < NS; ++kk) acc = fmaf(Fm[i * NS + kk], v[kk], acc);
          Pn[TRI(i, j)] = acc;
        }
      }

      // Riccati convergence latch (checked every 4th step)
      if ((t & 3) == 3) {
        float dmax = 0.f;
#pragma unroll
        for (int idx = 0; idx < 36; ++idx)
          dmax = fmaxf(dmax, fabsf(Pn[idx] - P[idx]));
        frozen = dmax < FREEZE_EPS;
      }
#pragma unroll
      for (int idx = 0; idx < 36; ++idx) P[idx] = Pn[idx];
    }

    // ---- time update of mean: m = F mu ----
#pragma unroll
    for (int i = 0; i < NS; ++i) {
      float acc = 0.f;
#pragma unroll
      for (int j = 0; j < NS; ++j) acc = fmaf(Fm[i * NS + j], mu_[j], acc);
      m[i] = acc;
    }
  }
}

extern "C" void kernel_launch(void* const* d_in, const int* in_sizes, int n_in,
                              void* d_out, int out_size, void* d_ws, size_t ws_size,
                              hipStream_t stream) {
  const float* x  = (const float*)d_in[0];
  const float* m0 = (const float*)d_in[1];
  const float* P0 = (const float*)d_in[2];
  const float* F  = (const float*)d_in[3];
  const float* Q  = (const float*)d_in[4];
  const float* H  = (const float*)d_in[5];
  const float* R  = (const float*)d_in[6];
  float* out = (float*)d_out;

  dim3 grid(NG / 64), block(64);
  hipLaunchKernelGGL(kf_kernel, grid, block, 0, stream,
                     x, m0, P0, F, Q, H, R, out);
}

// Round 2
// 437.536 us; speedup vs baseline: 1.6710x; 1.6710x over previous
//
#include <hip/hip_runtime.h>

#define NG 16384
#define NT 200
#define FREEZE_EPS 3e-5f

// xor-shuffle within 8-lane group (ds_swizzle BitMode: and=0x1f, or=0, xor=m)
#define XOR8(v, m) __int_as_float(__builtin_amdgcn_ds_swizzle(__float_as_int(v), (((m) << 10) | 0x1f)))
// broadcast from wave lane (addr = srclane*4, precomputed)
#define BPERM(v, a) __int_as_float(__builtin_amdgcn_ds_bpermute((a), __float_as_int(v)))

__global__ __launch_bounds__(256, 2)
void kf_kernel(const float* __restrict__ x,
               const float* __restrict__ m0,
               const float* __restrict__ P0,
               const float* __restrict__ Fm,
               const float* __restrict__ Qm,
               const float* __restrict__ Hm,
               const float* __restrict__ Rm,
               float* __restrict__ out) {
  const int tid  = threadIdx.x;
  const int lane = tid & 63;
  const int r    = tid & 7;                 // row owned within group
  const int g    = blockIdx.x * 32 + (tid >> 3);

  // ---- wave-uniform parameters (compiler -> s_load / SGPR) ----
  float Fs[64];
#pragma unroll
  for (int i = 0; i < 64; ++i) Fs[i] = Fm[i];
  float Hs0[8], Hs1[8];
#pragma unroll
  for (int i = 0; i < 8; ++i) { Hs0[i] = Hm[i]; Hs1[i] = Hm[8 + i]; }
  const float R00 = Rm[0], R01 = Rm[1], R11 = Rm[3];

  // ---- per-lane rows of F and Q ----
  float Frow[8], Qrow[8];
#pragma unroll
  for (int j = 0; j < 8; ++j) { Frow[j] = Fm[r * 8 + j]; Qrow[j] = Qm[r * 8 + j]; }
  const float H0r = Hm[r], H1r = Hm[8 + r];

  // precomputed bpermute byte-addresses for broadcast-from-octet-lane-j
  int bp[8];
#pragma unroll
  for (int j = 0; j < 8; ++j) bp[j] = (((lane & 56) | j) << 2);

  // ---- per-group state: lane r holds m[r] and P[r][0..7] ----
  float m = m0[(size_t)g * 8 + r];
  float P[8];
  {
    const float4* p0v = reinterpret_cast<const float4*>(P0 + (size_t)g * 64 + r * 8);
    float4 a = p0v[0], b = p0v[1];
    P[0] = a.x; P[1] = a.y; P[2] = a.z; P[3] = a.w;
    P[4] = b.x; P[5] = b.y; P[6] = b.z; P[7] = b.w;
  }

  const float* xg = x + (size_t)g * NT * 2;
  float* mo = out + (size_t)g * NT * 2;                         // means [G,T,2]
  float* co = out + (size_t)NG * NT * 2 + (size_t)g * NT * 4;   // covs  [G,T,2,2]

  float Kt0r = 0.f, Kt1r = 0.f, s00 = 0.f, s01 = 0.f, s11 = 0.f;
  float Pold[8];
  bool frozen = false;

#pragma unroll 1
  for (int t = 0; t < NT; ++t) {
    const float2 xt = *reinterpret_cast<const float2*>(xg + 2 * t);

    // ---- measurement mean mm = H m : octet allreduce ----
    float mm0 = H0r * m, mm1 = H1r * m;
    mm0 += XOR8(mm0, 1); mm0 += XOR8(mm0, 2); mm0 += XOR8(mm0, 4);
    mm1 += XOR8(mm1, 1); mm1 += XOR8(mm1, 2); mm1 += XOR8(mm1, 4);

    if (!frozen) {
      const bool chk = ((t & 3) == 3);
      if (chk) {
#pragma unroll
        for (int j = 0; j < 8; ++j) Pold[j] = P[j];
      }
      // HP column r entirely local via P symmetry: HP0[r] = sum_l H0[l]*P[r][l]
      float hp0 = 0.f, hp1 = 0.f;
#pragma unroll
      for (int l = 0; l < 8; ++l) {
        hp0 = fmaf(Hs0[l], P[l], hp0);
        hp1 = fmaf(Hs1[l], P[l], hp1);
      }
      // S = HP H^T + R (3 octet allreduces)
      float ps00 = hp0 * H0r, ps01 = hp0 * H1r, ps11 = hp1 * H1r;
      ps00 += XOR8(ps00, 1); ps00 += XOR8(ps00, 2); ps00 += XOR8(ps00, 4);
      ps01 += XOR8(ps01, 1); ps01 += XOR8(ps01, 2); ps01 += XOR8(ps01, 4);
      ps11 += XOR8(ps11, 1); ps11 += XOR8(ps11, 2); ps11 += XOR8(ps11, 4);
      s00 = R00 + ps00; s01 = R01 + ps01; s11 = R11 + ps11;
      // 2x2 inverse
      const float det  = fmaf(s00, s11, -(s01 * s01));
      const float rdet = 1.0f / det;
      const float i00 = s11 * rdet, i01 = -s01 * rdet, i11 = s00 * rdet;
      // Kt column r (local)
      Kt0r = i00 * hp0 + i01 * hp1;
      Kt1r = i01 * hp0 + i11 * hp1;
      // allgather HP columns (16 broadcasts)
      float HP0g[8], HP1g[8];
#pragma unroll
      for (int j = 0; j < 8; ++j) {
        HP0g[j] = BPERM(hp0, bp[j]);
        HP1g[j] = BPERM(hp1, bp[j]);
      }
      // Pu row r (overwrite P): Pu[r][j] = P[r][j] - Kt0[r]HP0[j] - Kt1[r]HP1[j]
#pragma unroll
      for (int j = 0; j < 8; ++j)
        P[j] = P[j] - Kt0r * HP0g[j] - Kt1r * HP1g[j];
      // V[r][j] = sum_l Pu[r][l] * F[j][l]   (local, F uniform)
      float V[8];
#pragma unroll
      for (int j = 0; j < 8; ++j) {
        float acc = 0.f;
#pragma unroll
        for (int l = 0; l < 8; ++l) acc = fmaf(P[l], Fs[j * 8 + l], acc);
        V[j] = acc;
      }
      // Pn[r][j] = Q[r][j] + sum_k F[r][k] * V[k][j]  (broadcast V rows)
      float Pn[8];
#pragma unroll
      for (int j = 0; j < 8; ++j) Pn[j] = Qrow[j];
#pragma unroll
      for (int k = 0; k < 8; ++k) {
#pragma unroll
        for (int j = 0; j < 8; ++j)
          Pn[j] = fmaf(Frow[k], BPERM(V[j], bp[k]), Pn[j]);
      }
      // Riccati convergence latch (octet-uniform)
      if (chk) {
        float d = 0.f;
#pragma unroll
        for (int j = 0; j < 8; ++j) d = fmaxf(d, fabsf(Pn[j] - Pold[j]));
        d = fmaxf(d, XOR8(d, 1)); d = fmaxf(d, XOR8(d, 2)); d = fmaxf(d, XOR8(d, 4));
        frozen = d < FREEZE_EPS;
      }
#pragma unroll
      for (int j = 0; j < 8; ++j) P[j] = Pn[j];
    }

    // ---- outputs (pre-update) ----
    if (r == 0) {
      *reinterpret_cast<float2*>(mo + 2 * t) = make_float2(mm0, mm1);
      *reinterpret_cast<float4*>(co + 4 * t) = make_float4(s00, s01, s01, s11);
    }

    // ---- measurement update + time update of mean ----
    const float y0 = xt.x - mm0, y1 = xt.y - mm1;
    const float mu = m + Kt0r * y0 + Kt1r * y1;   // updated mean, row r
    float acc = 0.f;
#pragma unroll
    for (int j = 0; j < 8; ++j) acc = fmaf(Frow[j], BPERM(mu, bp[j]), acc);
    m = acc;                                       // m = F mu
  }
}

extern "C" void kernel_launch(void* const* d_in, const int* in_sizes, int n_in,
                              void* d_out, int out_size, void* d_ws, size_t ws_size,
                              hipStream_t stream) {
  const float* x  = (const float*)d_in[0];
  const float* m0 = (const float*)d_in[1];
  const float* P0 = (const float*)d_in[2];
  const float* F  = (const float*)d_in[3];
  const float* Q  = (const float*)d_in[4];
  const float* H  = (const float*)d_in[5];
  const float* R  = (const float*)d_in[6];
  float* out = (float*)d_out;

  dim3 grid(NG * 8 / 256), block(256);
  hipLaunchKernelGGL(kf_kernel, grid, block, 0, stream,
                     x, m0, P0, F, Q, H, R, out);
}

// Round 3
// 380.202 us; speedup vs baseline: 1.9229x; 1.1508x over previous
//
#include <hip/hip_runtime.h>

#define NG 16384
#define NT 200
#define FREEZE_EPS 3e-5f

// DPP cross-lane (VALU pipe): all within aligned 8-lane octets
#define DPPF(v, ctrl) __int_as_float(__builtin_amdgcn_update_dpp( \
    0, __float_as_int(v), (ctrl), 0xF, 0xF, true))
#define QP1(v) DPPF(v, 0xB1)   // quad_perm [1,0,3,2] : src lane ^ 1
#define QP2(v) DPPF(v, 0x4E)   // quad_perm [2,3,0,1] : src lane ^ 2
#define RHM(v) DPPF(v, 0x141)  // row_half_mirror     : src lane = 7-l in octet
// LDS-pipe broadcast (used only where batched/independent)
#define BPERM(v, a) __int_as_float(__builtin_amdgcn_ds_bpermute((a), __float_as_int(v)))

__device__ __forceinline__ float allred8(float v) {
  v += QP1(v); v += QP2(v); v += RHM(v); return v;
}
__device__ __forceinline__ float allmax8(float v) {
  v = fmaxf(v, QP1(v)); v = fmaxf(v, QP2(v)); v = fmaxf(v, RHM(v)); return v;
}
// reduce-scatter butterfly: lane r gets sum_k Fd-weighted contributions.
// Fd[s] = F[(r^delta[s])][r], delta = [0,1,2,3,7,6,5,4].
__device__ __forceinline__ float matvec8(const float* __restrict__ Fd, float val) {
  float c0 = Fd[0] * val, c1 = Fd[1] * val, c2 = Fd[2] * val, c3 = Fd[3] * val;
  float c4 = Fd[4] * val, c5 = Fd[5] * val, c6 = Fd[6] * val, c7 = Fd[7] * val;
  float a0 = c0 + RHM(c4), a1 = c1 + RHM(c5), a2 = c2 + RHM(c6), a3 = c3 + RHM(c7);
  float b0 = a0 + QP2(a2), b1 = a1 + QP2(a3);
  return b0 + QP1(b1);
}

__global__ __launch_bounds__(256, 2)
void kf_kernel(const float* __restrict__ x,
               const float* __restrict__ m0,
               const float* __restrict__ P0,
               const float* __restrict__ Fm,
               const float* __restrict__ Qm,
               const float* __restrict__ Hm,
               const float* __restrict__ Rm,
               float* __restrict__ out) {
  const int tid  = threadIdx.x;
  const int lane = tid & 63;
  const int r    = tid & 7;
  const int g    = blockIdx.x * 32 + (tid >> 3);

  // ---- wave-uniform parameters (scalarized into SGPRs) ----
  float Fs[64];
#pragma unroll
  for (int i = 0; i < 64; ++i) Fs[i] = Fm[i];
  float Hs0[8], Hs1[8];
#pragma unroll
  for (int i = 0; i < 8; ++i) { Hs0[i] = Hm[i]; Hs1[i] = Hm[8 + i]; }
  const float R00 = Rm[0], R01 = Rm[1], R11 = Rm[3];

  // ---- per-lane rows/cols ----
  constexpr int kDelta[8] = {0, 1, 2, 3, 7, 6, 5, 4};
  float Fd[8];      // Fd[s] = F[r ^ delta[s]][r]  (dest-relative column of F)
#pragma unroll
  for (int s = 0; s < 8; ++s) Fd[s] = Fm[((r ^ kDelta[s]) << 3) | r];
  float Frow[8], Qrow[8];
#pragma unroll
  for (int j = 0; j < 8; ++j) { Frow[j] = Fm[r * 8 + j]; Qrow[j] = Qm[r * 8 + j]; }
  const float H0r = Hm[r], H1r = Hm[8 + r];

  int bp[8];  // bpermute byte-addresses: octet lane j
#pragma unroll
  for (int j = 0; j < 8; ++j) bp[j] = (((lane & 56) | j) << 2);

  // ---- per-group state: lane r holds m[r], P[r][0..7] ----
  float m = m0[(size_t)g * 8 + r];
  float P[8];
  {
    const float4* p0v = reinterpret_cast<const float4*>(P0 + (size_t)g * 64 + r * 8);
    float4 a = p0v[0], b = p0v[1];
    P[0] = a.x; P[1] = a.y; P[2] = a.z; P[3] = a.w;
    P[4] = b.x; P[5] = b.y; P[6] = b.z; P[7] = b.w;
  }

  const float* xg = x + (size_t)g * NT * 2;
  float* mo = out + (size_t)g * NT * 2;
  float* co = out + (size_t)NG * NT * 2 + (size_t)g * NT * 4;

  float Kt0r = 0.f, Kt1r = 0.f, s00 = 0.f, s01 = 0.f, s11 = 0.f;
  float Pold[8];
  bool frozen = false;

  float2 xt = *reinterpret_cast<const float2*>(xg);  // t=0

#pragma unroll 1
  for (int t = 0; t < NT; ++t) {
    // prefetch next observation (one iteration ahead)
    const int tn = (t + 1 < NT) ? (t + 1) : (NT - 1);
    const float2 xt_next = *reinterpret_cast<const float2*>(xg + 2 * tn);

    // ---- measurement mean mm = H m (DPP allreduce, VALU only) ----
    float mm0 = allred8(H0r * m);
    float mm1 = allred8(H1r * m);

    if (!frozen) {
      const bool chk = ((t & 3) == 3);
      if (chk) {
#pragma unroll
        for (int j = 0; j < 8; ++j) Pold[j] = P[j];
      }
      // HP column r local via P symmetry
      float hp0 = 0.f, hp1 = 0.f;
#pragma unroll
      for (int l = 0; l < 8; ++l) {
        hp0 = fmaf(Hs0[l], P[l], hp0);
        hp1 = fmaf(Hs1[l], P[l], hp1);
      }
      // allgather HP columns early (LDS pipe; overlaps with DPP below)
      float HP0g[8], HP1g[8];
#pragma unroll
      for (int j = 0; j < 8; ++j) {
        HP0g[j] = BPERM(hp0, bp[j]);
        HP1g[j] = BPERM(hp1, bp[j]);
      }
      // S = HP H^T + R (DPP allreduce x3)
      s00 = R00 + allred8(hp0 * H0r);
      s01 = R01 + allred8(hp0 * H1r);
      s11 = R11 + allred8(hp1 * H1r);
      // 2x2 inverse
      const float det  = fmaf(s00, s11, -(s01 * s01));
      const float rdet = 1.0f / det;
      const float i00 = s11 * rdet, i01 = -s01 * rdet, i11 = s00 * rdet;
      Kt0r = i00 * hp0 + i01 * hp1;
      Kt1r = i01 * hp0 + i11 * hp1;
      // Pu row r: P[j] -= Kt0r*HP0[j] + Kt1r*HP1[j]
#pragma unroll
      for (int j = 0; j < 8; ++j)
        P[j] = P[j] - Kt0r * HP0g[j] - Kt1r * HP1g[j];
      // V[r][j] = sum_l Pu[r][l] * F[j][l]  (local; F from SGPRs)
      float V[8];
#pragma unroll
      for (int j = 0; j < 8; ++j) {
        float acc = 0.f;
#pragma unroll
        for (int l = 0; l < 8; ++l) acc = fmaf(P[l], Fs[j * 8 + l], acc);
        V[j] = acc;
      }
      // Pn[r][j] = Q[r][j] + sum_k F[r][k] * V[k][j]  (batched bpermute)
      float Pn[8];
#pragma unroll
      for (int j = 0; j < 8; ++j) Pn[j] = Qrow[j];
#pragma unroll
      for (int k = 0; k < 8; ++k) {
#pragma unroll
        for (int j = 0; j < 8; ++j)
          Pn[j] = fmaf(Frow[k], BPERM(V[j], bp[k]), Pn[j]);
      }
      // Riccati convergence latch (octet-uniform)
      if (chk) {
        float d = 0.f;
#pragma unroll
        for (int j = 0; j < 8; ++j) d = fmaxf(d, fabsf(Pn[j] - Pold[j]));
        frozen = allmax8(d) < FREEZE_EPS;
      }
#pragma unroll
      for (int j = 0; j < 8; ++j) P[j] = Pn[j];
    }

    // ---- outputs (pre-update), split across lanes 0/1 ----
    if (r == 0) *reinterpret_cast<float2*>(mo + 2 * t) = make_float2(mm0, mm1);
    if (r == 1) *reinterpret_cast<float4*>(co + 4 * t) = make_float4(s00, s01, s01, s11);

    // ---- measurement update + time update of mean (DPP reduce-scatter) ----
    const float y0 = xt.x - mm0, y1 = xt.y - mm1;
    const float mu = m + Kt0r * y0 + Kt1r * y1;
    m = matvec8(Fd, mu);          // m = F mu
    xt = xt_next;
  }
}

extern "C" void kernel_launch(void* const* d_in, const int* in_sizes, int n_in,
                              void* d_out, int out_size, void* d_ws, size_t ws_size,
                              hipStream_t stream) {
  const float* x  = (const float*)d_in[0];
  const float* m0 = (const float*)d_in[1];
  const float* P0 = (const float*)d_in[2];
  const float* F  = (const float*)d_in[3];
  const float* Q  = (const float*)d_in[4];
  const float* H  = (const float*)d_in[5];
  const float* R  = (const float*)d_in[6];
  float* out = (float*)d_out;

  dim3 grid(NG * 8 / 256), block(256);
  hipLaunchKernelGGL(kf_kernel, grid, block, 0, stream,
                     x, m0, P0, F, Q, H, R, out);
}

// Round 4
// 241.970 us; speedup vs baseline: 3.0215x; 1.5713x over previous
//
#include <hip/hip_runtime.h>

#define NG 16384
#define NT 200
#define FREEZE_EPS 3e-5f

// DPP cross-lane (VALU pipe), all within aligned 8-lane octets
#define DPPF(v, ctrl) __int_as_float(__builtin_amdgcn_update_dpp( \
    0, __float_as_int(v), (ctrl), 0xF, 0xF, true))
#define QP1(v) DPPF(v, 0xB1)   // src lane ^ 1
#define QP2(v) DPPF(v, 0x4E)   // src lane ^ 2
#define RHM(v) DPPF(v, 0x141)  // src lane ^ 7 (row_half_mirror)
// LDS-pipe broadcast (only for the 16 HP allgathers)
#define BPERM(v, a) __int_as_float(__builtin_amdgcn_ds_bpermute((a), __float_as_int(v)))

__device__ __forceinline__ float allred8(float v) {
  v += QP1(v); v += QP2(v); v += RHM(v); return v;
}
__device__ __forceinline__ float allmax8(float v) {
  v = fmaxf(v, QP1(v)); v = fmaxf(v, QP2(v)); v = fmaxf(v, RHM(v)); return v;
}
// reduce-scatter butterfly: lane r ends with sum_k F[r][k]*val[k].
// Fd[s] = F[r^kd[s]][r], kd = [0,1,2,3,7,6,5,4].
__device__ __forceinline__ float matvec8(const float* __restrict__ Fd, float val) {
  float c0 = Fd[0]*val, c1 = Fd[1]*val, c2 = Fd[2]*val, c3 = Fd[3]*val;
  float c4 = Fd[4]*val, c5 = Fd[5]*val, c6 = Fd[6]*val, c7 = Fd[7]*val;
  float a0 = c0 + RHM(c4), a1 = c1 + RHM(c5), a2 = c2 + RHM(c6), a3 = c3 + RHM(c7);
  float b0 = a0 + QP2(a2), b1 = a1 + QP2(a3);
  return b0 + QP1(b1);
}

__global__ __launch_bounds__(256, 2)
void kf_kernel(const float* __restrict__ x,
               const float* __restrict__ m0,
               const float* __restrict__ P0,
               const float* __restrict__ Fm,
               const float* __restrict__ Qm,
               const float* __restrict__ Hm,
               const float* __restrict__ Rm,
               float* __restrict__ out) {
  const int tid  = threadIdx.x;
  const int lane = tid & 63;
  const int r    = tid & 7;
  const int g    = blockIdx.x * 32 + (tid >> 3);

  // ---- wave-uniform parameters (scalarized to SGPRs) ----
  float Fs[64];
#pragma unroll
  for (int i = 0; i < 64; ++i) Fs[i] = Fm[i];
  float Hs0[8], Hs1[8];
#pragma unroll
  for (int i = 0; i < 8; ++i) { Hs0[i] = Hm[i]; Hs1[i] = Hm[8 + i]; }
  const float R00 = Rm[0], R01 = Rm[1], R11 = Rm[3];

  // ---- per-lane permuted coefficient vectors ----
  constexpr int kD[8] = {0, 1, 2, 3, 7, 6, 5, 4};
  float Fd[8], Fperm[8], Qrow[8];
#pragma unroll
  for (int s = 0; s < 8; ++s) {
    Fd[s]    = Fm[((r ^ kD[s]) << 3) | r];   // F[r^kd[s]][r]
    Fperm[s] = Fm[(r << 3) | (r ^ kD[s])];   // F[r][r^kd[s]]
  }
#pragma unroll
  for (int j = 0; j < 8; ++j) Qrow[j] = Qm[r * 8 + j];
  const float H0r = Hm[r], H1r = Hm[8 + r];

  int bp[8];  // bpermute byte-addresses for octet lane j
#pragma unroll
  for (int j = 0; j < 8; ++j) bp[j] = (((lane & 56) | j) << 2);

  // ---- per-group state: lane r holds m[r], P[r][0..7] ----
  float m = m0[(size_t)g * 8 + r];
  float P[8];
  {
    const float4* p0v = reinterpret_cast<const float4*>(P0 + (size_t)g * 64 + r * 8);
    float4 a = p0v[0], b = p0v[1];
    P[0] = a.x; P[1] = a.y; P[2] = a.z; P[3] = a.w;
    P[4] = b.x; P[5] = b.y; P[6] = b.z; P[7] = b.w;
  }

  const float* xg = x + (size_t)g * NT * 2;
  float* mo = out + (size_t)g * NT * 2;
  float* co = out + (size_t)NG * NT * 2 + (size_t)g * NT * 4;

  float Kt0r = 0.f, Kt1r = 0.f, s00 = 0.f, s01 = 0.f, s11 = 0.f;
  float Pold[8];
  bool frozen = false;

  float2 xt = *reinterpret_cast<const float2*>(xg);  // t=0

#pragma unroll 1
  for (int t = 0; t < NT; ++t) {
    const int tn = (t + 1 < NT) ? (t + 1) : (NT - 1);
    const float2 xt_next = *reinterpret_cast<const float2*>(xg + 2 * tn);

    // ---- measurement mean mm = H m ----
    float mm0 = allred8(H0r * m);
    float mm1 = allred8(H1r * m);

    if (!frozen) {
      const bool chk = ((t & 3) == 3);
      if (chk) {
#pragma unroll
        for (int j = 0; j < 8; ++j) Pold[j] = P[j];
      }
      // hp[r] = (H P)[.,r] via P symmetry — tree-summed
      float a0 = fmaf(Hs0[1], P[1], Hs0[0] * P[0]);
      float a1 = fmaf(Hs0[3], P[3], Hs0[2] * P[2]);
      float a2 = fmaf(Hs0[5], P[5], Hs0[4] * P[4]);
      float a3 = fmaf(Hs0[7], P[7], Hs0[6] * P[6]);
      const float hp0 = (a0 + a1) + (a2 + a3);
      float b0 = fmaf(Hs1[1], P[1], Hs1[0] * P[0]);
      float b1 = fmaf(Hs1[3], P[3], Hs1[2] * P[2]);
      float b2 = fmaf(Hs1[5], P[5], Hs1[4] * P[4]);
      float b3 = fmaf(Hs1[7], P[7], Hs1[6] * P[6]);
      const float hp1 = (b0 + b1) + (b2 + b3);

      // issue HP allgather early (LDS pipe, overlaps DPP work below)
      float HP0g[8], HP1g[8];
#pragma unroll
      for (int j = 0; j < 8; ++j) {
        HP0g[j] = BPERM(hp0, bp[j]);
        HP1g[j] = BPERM(hp1, bp[j]);
      }

      // S = HP H^T + R (DPP allreduce)
      s00 = R00 + allred8(hp0 * H0r);
      s01 = R01 + allred8(hp0 * H1r);
      s11 = R11 + allred8(hp1 * H1r);
      const float det  = fmaf(s00, s11, -(s01 * s01));
      const float rdet = 1.0f / det;
      const float i00 = s11 * rdet, i01 = -s01 * rdet, i11 = s00 * rdet;
      Kt0r = i00 * hp0 + i01 * hp1;
      Kt1r = i01 * hp0 + i11 * hp1;

      // Pu row r (overwrite P)
#pragma unroll
      for (int j = 0; j < 8; ++j)
        P[j] = P[j] - Kt0r * HP0g[j] - Kt1r * HP1g[j];

      // V[r][j] = sum_l Pu[r][l] * F[j][l]  (local, F in SGPRs, tree-summed)
      float V[8];
#pragma unroll
      for (int j = 0; j < 8; ++j) {
        float t0 = fmaf(P[1], Fs[j * 8 + 1], P[0] * Fs[j * 8 + 0]);
        float t1 = fmaf(P[3], Fs[j * 8 + 3], P[2] * Fs[j * 8 + 2]);
        float t2 = fmaf(P[5], Fs[j * 8 + 5], P[4] * Fs[j * 8 + 4]);
        float t3 = fmaf(P[7], Fs[j * 8 + 7], P[6] * Fs[j * 8 + 6]);
        V[j] = (t0 + t1) + (t2 + t3);
      }

      // Pn[r][j] = Q[r][j] + sum_s F[r][r^kd[s]] * V[r^kd[s]][j]
      // via DPP xor-tree allgather of whole V rows (payload j is absolute)
      float PnA[8], PnB[8], VA1[8], VA2[8], VA3[8], T[8], U[8];
#pragma unroll
      for (int j = 0; j < 8; ++j) PnA[j] = fmaf(Fperm[0], V[j], Qrow[j]);
#pragma unroll
      for (int j = 0; j < 8; ++j) VA1[j] = QP1(V[j]);       // row r^1
#pragma unroll
      for (int j = 0; j < 8; ++j) PnA[j] = fmaf(Fperm[1], VA1[j], PnA[j]);
#pragma unroll
      for (int j = 0; j < 8; ++j) VA2[j] = QP2(V[j]);       // row r^2
#pragma unroll
      for (int j = 0; j < 8; ++j) PnB[j] = Fperm[2] * VA2[j];
#pragma unroll
      for (int j = 0; j < 8; ++j) VA3[j] = QP2(VA1[j]);     // row r^3
#pragma unroll
      for (int j = 0; j < 8; ++j) PnB[j] = fmaf(Fperm[3], VA3[j], PnB[j]);
#pragma unroll
      for (int j = 0; j < 8; ++j) T[j] = RHM(V[j]);         // row r^7
#pragma unroll
      for (int j = 0; j < 8; ++j) PnA[j] = fmaf(Fperm[4], T[j], PnA[j]);
#pragma unroll
      for (int j = 0; j < 8; ++j) U[j] = RHM(VA1[j]);       // row r^6
#pragma unroll
      for (int j = 0; j < 8; ++j) PnB[j] = fmaf(Fperm[5], U[j], PnB[j]);
#pragma unroll
      for (int j = 0; j < 8; ++j) T[j] = RHM(VA2[j]);       // row r^5
#pragma unroll
      for (int j = 0; j < 8; ++j) PnA[j] = fmaf(Fperm[6], T[j], PnA[j]);
#pragma unroll
      for (int j = 0; j < 8; ++j) U[j] = RHM(VA3[j]);       // row r^4
#pragma unroll
      for (int j = 0; j < 8; ++j) PnB[j] = fmaf(Fperm[7], U[j], PnB[j]);

      if (chk) {
        float d = 0.f;
#pragma unroll
        for (int j = 0; j < 8; ++j) {
          const float pn = PnA[j] + PnB[j];
          d = fmaxf(d, fabsf(pn - Pold[j]));
          P[j] = pn;
        }
        frozen = allmax8(d) < FREEZE_EPS;
      } else {
#pragma unroll
        for (int j = 0; j < 8; ++j) P[j] = PnA[j] + PnB[j];
      }
    }

    // ---- outputs (pre-update), split across lanes 0/1 ----
    if (r == 0) *reinterpret_cast<float2*>(mo + 2 * t) = make_float2(mm0, mm1);
    if (r == 1) *reinterpret_cast<float4*>(co + 4 * t) = make_float4(s00, s01, s01, s11);

    // ---- mean update + time update (all DPP) ----
    const float y0 = xt.x - mm0, y1 = xt.y - mm1;
    const float mu = m + Kt0r * y0 + Kt1r * y1;
    m = matvec8(Fd, mu);   // m = F mu
    xt = xt_next;
  }
}

extern "C" void kernel_launch(void* const* d_in, const int* in_sizes, int n_in,
                              void* d_out, int out_size, void* d_ws, size_t ws_size,
                              hipStream_t stream) {
  const float* x  = (const float*)d_in[0];
  const float* m0 = (const float*)d_in[1];
  const float* P0 = (const float*)d_in[2];
  const float* F  = (const float*)d_in[3];
  const float* Q  = (const float*)d_in[4];
  const float* H  = (const float*)d_in[5];
  const float* R  = (const float*)d_in[6];
  float* out = (float*)d_out;

  dim3 grid(NG * 8 / 256), block(256);
  hipLaunchKernelGGL(kf_kernel, grid, block, 0, stream,
                     x, m0, P0, F, Q, H, R, out);
}

// Round 5
// 228.886 us; speedup vs baseline: 3.1942x; 1.0572x over previous
//
#include <hip/hip_runtime.h>

#define NG 16384
#define NT 200
#define FREEZE_EPS 3e-4f

typedef float v2f __attribute__((ext_vector_type(2)));

// DPP cross-lane (VALU pipe), all within aligned 8-lane octets
#define DPPI(v, ctrl) __builtin_amdgcn_update_dpp(0, (v), (ctrl), 0xF, 0xF, true)
#define DPPF(v, ctrl) __int_as_float(DPPI(__float_as_int(v), (ctrl)))
#define QP1(v) DPPF(v, 0xB1)   // src lane ^ 1
#define QP2(v) DPPF(v, 0x4E)   // src lane ^ 2
#define RHM(v) DPPF(v, 0x141)  // src lane ^ 7 (row_half_mirror)
#define BPERM(v, a) __int_as_float(__builtin_amdgcn_ds_bpermute((a), __float_as_int(v)))

static __device__ __forceinline__ v2f qp1v(v2f a) { return v2f{QP1(a[0]), QP1(a[1])}; }
static __device__ __forceinline__ v2f qp2v(v2f a) { return v2f{QP2(a[0]), QP2(a[1])}; }
static __device__ __forceinline__ v2f rhmv(v2f a) { return v2f{RHM(a[0]), RHM(a[1])}; }
static __device__ __forceinline__ v2f fmav(v2f a, v2f b, v2f c) {
  return __builtin_elementwise_fma(a, b, c);
}
static __device__ __forceinline__ v2f splat(float x) { return v2f{x, x}; }

__device__ __forceinline__ float allred8(float v) {
  v += QP1(v); v += QP2(v); v += RHM(v); return v;
}
__device__ __forceinline__ v2f allred8v(v2f v) {
  v += qp1v(v); v += qp2v(v); v += rhmv(v); return v;
}
__device__ __forceinline__ float allmax8(float v) {
  v = fmaxf(v, QP1(v)); v = fmaxf(v, QP2(v)); v = fmaxf(v, RHM(v)); return v;
}
// reduce-scatter butterfly: lane r ends with sum_k F[r][k]*val[k].
// Fd[s] = F[r^kd[s]][r], kd = [0,1,2,3,7,6,5,4].
__device__ __forceinline__ float matvec8(const float* __restrict__ Fd, float val) {
  float c0 = Fd[0]*val, c1 = Fd[1]*val, c2 = Fd[2]*val, c3 = Fd[3]*val;
  float c4 = Fd[4]*val, c5 = Fd[5]*val, c6 = Fd[6]*val, c7 = Fd[7]*val;
  float a0 = c0 + RHM(c4), a1 = c1 + RHM(c5), a2 = c2 + RHM(c6), a3 = c3 + RHM(c7);
  float b0 = a0 + QP2(a2), b1 = a1 + QP2(a3);
  return b0 + QP1(b1);
}

__global__ __launch_bounds__(256, 2)
void kf_kernel(const float* __restrict__ x,
               const float* __restrict__ m0,
               const float* __restrict__ P0,
               const float* __restrict__ Fm,
               const float* __restrict__ Qm,
               const float* __restrict__ Hm,
               const float* __restrict__ Rm,
               float* __restrict__ out) {
  const int tid  = threadIdx.x;
  const int lane = tid & 63;
  const int r    = tid & 7;
  const int g    = blockIdx.x * 32 + (tid >> 3);

  // ---- wave-uniform parameters (scalarized to SGPRs) ----
  // Fp[c][l] = (F[2c][l], F[2c+1][l])  — column-pair packed for v_pk_fma
  v2f Fp[4][8];
#pragma unroll
  for (int c = 0; c < 4; ++c)
#pragma unroll
    for (int l = 0; l < 8; ++l)
      Fp[c][l] = v2f{Fm[(2 * c) * 8 + l], Fm[(2 * c + 1) * 8 + l]};
  v2f Hpk[8];  // (H0[l], H1[l])
#pragma unroll
  for (int l = 0; l < 8; ++l) Hpk[l] = v2f{Hm[l], Hm[8 + l]};
  const float R00 = Rm[0], R01 = Rm[1], R11 = Rm[3];

  // ---- per-lane permuted coefficient vectors ----
  constexpr int kD[8] = {0, 1, 2, 3, 7, 6, 5, 4};
  float Fd[8], Fperm[8];
#pragma unroll
  for (int s = 0; s < 8; ++s) {
    Fd[s]    = Fm[((r ^ kD[s]) << 3) | r];   // F[r^kd[s]][r]
    Fperm[s] = Fm[(r << 3) | (r ^ kD[s])];   // F[r][r^kd[s]]
  }
  v2f Qp[4];
#pragma unroll
  for (int c = 0; c < 4; ++c) Qp[c] = v2f{Qm[r * 8 + 2 * c], Qm[r * 8 + 2 * c + 1]};
  const v2f HrPk = v2f{Hm[r], Hm[8 + r]};

  int bp[8];  // bpermute byte-addresses for octet lane j
#pragma unroll
  for (int j = 0; j < 8; ++j) bp[j] = (((lane & 56) | j) << 2);

  // ---- per-group state: lane r holds m[r], P[r][0..7] packed ----
  float m = m0[(size_t)g * 8 + r];
  v2f Pp[4];
  {
    const float4* p0v = reinterpret_cast<const float4*>(P0 + (size_t)g * 64 + r * 8);
    float4 a = p0v[0], b = p0v[1];
    Pp[0] = v2f{a.x, a.y}; Pp[1] = v2f{a.z, a.w};
    Pp[2] = v2f{b.x, b.y}; Pp[3] = v2f{b.z, b.w};
  }

  const float* xg = x + (size_t)g * NT * 2;
  float* mo = out + (size_t)g * NT * 2;
  float* co = out + (size_t)NG * NT * 2 + (size_t)g * NT * 4;

  float Kt0r = 0.f, Kt1r = 0.f, s00 = 0.f, s01 = 0.f, s11 = 0.f;
  v2f Pold[4];
  bool frozen = false;

  v2f xt = *reinterpret_cast<const v2f*>(xg);  // t=0

#pragma unroll 1
  for (int t = 0; t < NT; ++t) {
    const int tn = (t + 1 < NT) ? (t + 1) : (NT - 1);
    const v2f xt_next = *reinterpret_cast<const v2f*>(xg + 2 * tn);

    // ---- measurement mean (mm0,mm1) = H m : packed DPP allreduce ----
    v2f mm = allred8v(splat(m) * HrPk);

    if (!frozen) {
      const bool chk = ((t & 3) == 3);
      if (chk) {
#pragma unroll
        for (int c = 0; c < 4; ++c) Pold[c] = Pp[c];
      }
      // hp = ((HP)[0][r], (HP)[1][r]) via P symmetry — packed, 2 accumulators
      v2f hA = splat(Pp[0][0]) * Hpk[0];
      v2f hB = splat(Pp[0][1]) * Hpk[1];
      hA = fmav(splat(Pp[1][0]), Hpk[2], hA);
      hB = fmav(splat(Pp[1][1]), Hpk[3], hB);
      hA = fmav(splat(Pp[2][0]), Hpk[4], hA);
      hB = fmav(splat(Pp[2][1]), Hpk[5], hB);
      hA = fmav(splat(Pp[3][0]), Hpk[6], hA);
      hB = fmav(splat(Pp[3][1]), Hpk[7], hB);
      const v2f hp = hA + hB;
      const float hp0 = hp[0], hp1 = hp[1];

      // issue HP allgather early (LDS pipe; overlaps DPP work below)
      float HP0g[8], HP1g[8];
#pragma unroll
      for (int j = 0; j < 8; ++j) {
        HP0g[j] = BPERM(hp0, bp[j]);
        HP1g[j] = BPERM(hp1, bp[j]);
      }

      // S = HP H^T + R : packed allreduce for (s00,s01), scalar for s11
      v2f ps = allred8v(splat(hp0) * HrPk);
      s00 = R00 + ps[0];
      s01 = R01 + ps[1];
      s11 = R11 + allred8(hp1 * HrPk[1]);
      const float det  = fmaf(s00, s11, -(s01 * s01));
      const float rdet = 1.0f / det;
      const float i00 = s11 * rdet, i01 = -s01 * rdet, i11 = s00 * rdet;
      Kt0r = i00 * hp0 + i01 * hp1;
      Kt1r = i01 * hp0 + i11 * hp1;

      // Pu row r (packed): Pp[c] -= Kt0r*HP0[pair] + Kt1r*HP1[pair]
#pragma unroll
      for (int c = 0; c < 4; ++c) {
        const v2f h0p = v2f{HP0g[2 * c], HP0g[2 * c + 1]};
        const v2f h1p = v2f{HP1g[2 * c], HP1g[2 * c + 1]};
        Pp[c] = fmav(splat(-Kt0r), h0p, fmav(splat(-Kt1r), h1p, Pp[c]));
      }

      // V[r][2c..2c+1] = sum_l Pu[r][l] * (F[2c][l],F[2c+1][l])  — packed
      v2f Vp[4];
#pragma unroll
      for (int c = 0; c < 4; ++c) {
        v2f vA = splat(Pp[0][0]) * Fp[c][0];
        v2f vB = splat(Pp[0][1]) * Fp[c][1];
        vA = fmav(splat(Pp[1][0]), Fp[c][2], vA);
        vB = fmav(splat(Pp[1][1]), Fp[c][3], vB);
        vA = fmav(splat(Pp[2][0]), Fp[c][4], vA);
        vB = fmav(splat(Pp[2][1]), Fp[c][5], vB);
        vA = fmav(splat(Pp[3][0]), Fp[c][6], vA);
        vB = fmav(splat(Pp[3][1]), Fp[c][7], vB);
        Vp[c] = vA + vB;
      }

      // Pn[r][.] = Q[r][.] + sum_s F[r][r^kd[s]] * V[r^kd[s]][.]
      // DPP xor-tree allgather of whole packed V rows
      v2f PnA[4], PnB[4], VA1[4], VA2[4], VA3[4], Tt[4], Uu[4];
#pragma unroll
      for (int c = 0; c < 4; ++c) PnA[c] = fmav(splat(Fperm[0]), Vp[c], Qp[c]);
#pragma unroll
      for (int c = 0; c < 4; ++c) VA1[c] = qp1v(Vp[c]);        // row r^1
#pragma unroll
      for (int c = 0; c < 4; ++c) PnA[c] = fmav(splat(Fperm[1]), VA1[c], PnA[c]);
#pragma unroll
      for (int c = 0; c < 4; ++c) VA2[c] = qp2v(Vp[c]);        // row r^2
#pragma unroll
      for (int c = 0; c < 4; ++c) PnB[c] = splat(Fperm[2]) * VA2[c];
#pragma unroll
      for (int c = 0; c < 4; ++c) VA3[c] = qp2v(VA1[c]);       // row r^3
#pragma unroll
      for (int c = 0; c < 4; ++c) PnB[c] = fmav(splat(Fperm[3]), VA3[c], PnB[c]);
#pragma unroll
      for (int c = 0; c < 4; ++c) Tt[c] = rhmv(Vp[c]);         // row r^7
#pragma unroll
      for (int c = 0; c < 4; ++c) PnA[c] = fmav(splat(Fperm[4]), Tt[c], PnA[c]);
#pragma unroll
      for (int c = 0; c < 4; ++c) Uu[c] = rhmv(VA1[c]);        // row r^6
#pragma unroll
      for (int c = 0; c < 4; ++c) PnB[c] = fmav(splat(Fperm[5]), Uu[c], PnB[c]);
#pragma unroll
      for (int c = 0; c < 4; ++c) Tt[c] = rhmv(VA2[c]);        // row r^5
#pragma unroll
      for (int c = 0; c < 4; ++c) PnA[c] = fmav(splat(Fperm[6]), Tt[c], PnA[c]);
#pragma unroll
      for (int c = 0; c < 4; ++c) Uu[c] = rhmv(VA3[c]);        // row r^4
#pragma unroll
      for (int c = 0; c < 4; ++c) PnB[c] = fmav(splat(Fperm[7]), Uu[c], PnB[c]);

      if (chk) {
        float d = 0.f;
#pragma unroll
        for (int c = 0; c < 4; ++c) {
          const v2f pn = PnA[c] + PnB[c];
          d = fmaxf(d, fabsf(pn[0] - Pold[c][0]));
          d = fmaxf(d, fabsf(pn[1] - Pold[c][1]));
          Pp[c] = pn;
        }
        frozen = allmax8(d) < FREEZE_EPS;
      } else {
#pragma unroll
        for (int c = 0; c < 4; ++c) Pp[c] = PnA[c] + PnB[c];
      }
    }

    // ---- outputs (pre-update), split across lanes 0/1 ----
    if (r == 0) *reinterpret_cast<float2*>(mo + 2 * t) = make_float2(mm[0], mm[1]);
    if (r == 1) *reinterpret_cast<float4*>(co + 4 * t) = make_float4(s00, s01, s01, s11);

    // ---- mean update + time update (all DPP) ----
    const v2f y = xt - mm;
    const float mu = fmaf(Kt0r, y[0], fmaf(Kt1r, y[1], m));
    m = matvec8(Fd, mu);   // m = F mu
    xt = xt_next;
  }
}

extern "C" void kernel_launch(void* const* d_in, const int* in_sizes, int n_in,
                              void* d_out, int out_size, void* d_ws, size_t ws_size,
                              hipStream_t stream) {
  const float* x  = (const float*)d_in[0];
  const float* m0 = (const float*)d_in[1];
  const float* P0 = (const float*)d_in[2];
  const float* F  = (const float*)d_in[3];
  const float* Q  = (const float*)d_in[4];
  const float* H  = (const float*)d_in[5];
  const float* R  = (const float*)d_in[6];
  float* out = (float*)d_out;

  dim3 grid(NG * 8 / 256), block(256);
  hipLaunchKernelGGL(kf_kernel, grid, block, 0, stream,
                     x, m0, P0, F, Q, H, R, out);
}

// Round 6
// 222.802 us; speedup vs baseline: 3.2814x; 1.0273x over previous
//
#include <hip/hip_runtime.h>

#define NG 16384
#define NT 200
#define FREEZE_EPS 3e-4f

// DPP cross-lane (VALU pipe), all within aligned 8-lane octets
#define DPPF(v, ctrl) __int_as_float(__builtin_amdgcn_update_dpp( \
    0, __float_as_int(v), (ctrl), 0xF, 0xF, true))
#define QP1(v) DPPF(v, 0xB1)   // src lane ^ 1
#define QP2(v) DPPF(v, 0x4E)   // src lane ^ 2
#define RHM(v) DPPF(v, 0x141)  // src lane ^ 7 (row_half_mirror)

__device__ __forceinline__ float allred8(float v) {
  v += QP1(v); v += QP2(v); v += RHM(v); return v;
}
__device__ __forceinline__ float allmax8(float v) {
  v = fmaxf(v, QP1(v)); v = fmaxf(v, QP2(v)); v = fmaxf(v, RHM(v)); return v;
}
// reduce-scatter butterfly: lane r ends with sum_k F[r][k]*val[k].
// Fd[s] = F[r^kd[s]][r], kd = [0,1,2,3,7,6,5,4].
__device__ __forceinline__ float matvec8(const float* __restrict__ Fd, float val) {
  float c0 = Fd[0]*val, c1 = Fd[1]*val, c2 = Fd[2]*val, c3 = Fd[3]*val;
  float c4 = Fd[4]*val, c5 = Fd[5]*val, c6 = Fd[6]*val, c7 = Fd[7]*val;
  float a0 = c0 + RHM(c4), a1 = c1 + RHM(c5), a2 = c2 + RHM(c6), a3 = c3 + RHM(c7);
  float b0 = a0 + QP2(a2), b1 = a1 + QP2(a3);
  return b0 + QP1(b1);
}

__global__ __launch_bounds__(256, 1)
void kf_kernel(const float* __restrict__ x,
               const float* __restrict__ m0,
               const float* __restrict__ P0,
               const float* __restrict__ Fm,
               const float* __restrict__ Qm,
               const float* __restrict__ Hm,
               const float* __restrict__ Rm,
               float* __restrict__ out) {
  const int tid = threadIdx.x;
  const int r   = tid & 7;
  const int g   = blockIdx.x * 32 + (tid >> 3);

  // ---- per-lane xor-indexed parameter tables ----
  constexpr int kD[8] = {0, 1, 2, 3, 7, 6, 5, 4};
  float Fd[8];   // F[r^kd[s]][r]  (for matvec8)
#pragma unroll
  for (int s = 0; s < 8; ++s) Fd[s] = Fm[((r ^ kD[s]) << 3) | r];
  float Frt[8];  // Frt[e] = F[r][r^e]  (row of F in xor layout; also Fperm)
  float Qt[8], Hd0[8], Hd1[8];
#pragma unroll
  for (int c = 0; c < 8; ++c) {
    Frt[c] = Fm[(r << 3) | (r ^ c)];
    Qt[c]  = Qm[(r << 3) | (r ^ c)];
    Hd0[c] = Hm[r ^ c];
    Hd1[c] = Hm[8 + (r ^ c)];
  }
  const float R00 = Rm[0], R01 = Rm[1], R11 = Rm[3];

  // ---- Fde[dl][c] = F[r^dl][r^c], built once via DPP chains ----
  float Fde[8][8];
  {
    float t1[8], t2[8], t3[8], tt[8];
#pragma unroll
    for (int c = 0; c < 8; ++c) Fde[0][c] = Frt[c];
#pragma unroll
    for (int c = 0; c < 8; ++c) t1[c] = QP1(Frt[c]);
#pragma unroll
    for (int c = 0; c < 8; ++c) Fde[1][c] = t1[1 ^ c];
#pragma unroll
    for (int c = 0; c < 8; ++c) t2[c] = QP2(Frt[c]);
#pragma unroll
    for (int c = 0; c < 8; ++c) Fde[2][c] = t2[2 ^ c];
#pragma unroll
    for (int c = 0; c < 8; ++c) t3[c] = QP2(t1[c]);
#pragma unroll
    for (int c = 0; c < 8; ++c) Fde[3][c] = t3[3 ^ c];
#pragma unroll
    for (int c = 0; c < 8; ++c) tt[c] = RHM(Frt[c]);
#pragma unroll
    for (int c = 0; c < 8; ++c) Fde[7][c] = tt[7 ^ c];
#pragma unroll
    for (int c = 0; c < 8; ++c) tt[c] = RHM(t1[c]);
#pragma unroll
    for (int c = 0; c < 8; ++c) Fde[6][c] = tt[6 ^ c];
#pragma unroll
    for (int c = 0; c < 8; ++c) tt[c] = RHM(t2[c]);
#pragma unroll
    for (int c = 0; c < 8; ++c) Fde[5][c] = tt[5 ^ c];
#pragma unroll
    for (int c = 0; c < 8; ++c) tt[c] = RHM(t3[c]);
#pragma unroll
    for (int c = 0; c < 8; ++c) Fde[4][c] = tt[4 ^ c];
  }

  // ---- per-group state: lane r holds m[r] and P~[d] = P[r][r^d] ----
  float m = m0[(size_t)g * 8 + r];
  float Pt[8];
#pragma unroll
  for (int d = 0; d < 8; ++d)
    Pt[d] = P0[(size_t)g * 64 + (r << 3) + (r ^ d)];

  const float* xg = x + (size_t)g * NT * 2;
  float* mo = out + (size_t)g * NT * 2;
  float* co = out + (size_t)NG * NT * 2 + (size_t)g * NT * 4;

  float kt0 = 0.f, kt1 = 0.f, s00 = 0.f, s01 = 0.f, s11 = 0.f;
  bool frozen = false;

  // ---- 8-deep x prefetch queue (full unroll keeps slots in registers) ----
  float2 q[8];
#pragma unroll
  for (int j = 0; j < 8; ++j) q[j] = *reinterpret_cast<const float2*>(xg + 2 * j);

#pragma unroll 1
  for (int tb = 0; tb < NT; tb += 8) {
#pragma unroll
    for (int j = 0; j < 8; ++j) {
      const int t = tb + j;
      const float2 xt = q[j];

      // ---- measurement mean mm = H m ----
      float mm0 = allred8(Hd0[0] * m);
      float mm1 = allred8(Hd1[0] * m);

      if (!frozen) {
        // hp_m = (H P)[m][r] via P symmetry (tree-summed, xor layout)
        float a0 = fmaf(Hd0[1], Pt[1], Hd0[0] * Pt[0]);
        float a1 = fmaf(Hd0[3], Pt[3], Hd0[2] * Pt[2]);
        float a2 = fmaf(Hd0[5], Pt[5], Hd0[4] * Pt[4]);
        float a3 = fmaf(Hd0[7], Pt[7], Hd0[6] * Pt[6]);
        const float hp0 = (a0 + a1) + (a2 + a3);
        float b0 = fmaf(Hd1[1], Pt[1], Hd1[0] * Pt[0]);
        float b1 = fmaf(Hd1[3], Pt[3], Hd1[2] * Pt[2]);
        float b2 = fmaf(Hd1[5], Pt[5], Hd1[4] * Pt[4]);
        float b3 = fmaf(Hd1[7], Pt[7], Hd1[6] * Pt[6]);
        const float hp1 = (b0 + b1) + (b2 + b3);

        // S = HP H^T + R (DPP allreduce)
        s00 = R00 + allred8(hp0 * Hd0[0]);
        s01 = R01 + allred8(hp0 * Hd1[0]);
        s11 = R11 + allred8(hp1 * Hd1[0]);
        const float det  = fmaf(s00, s11, -(s01 * s01));
        const float rdet = 1.0f / det;
        const float i00 = s11 * rdet, i01 = -s01 * rdet, i11 = s00 * rdet;
        kt0 = i00 * hp0 + i01 * hp1;   // Kt[0][r]
        kt1 = i01 * hp0 + i11 * hp1;   // Kt[1][r]

        // DPP allgather of hp into xor slots: G[d] = hp @ lane r^d
        float G0[8], G1[8];
        G0[0] = hp0;        G1[0] = hp1;
        G0[1] = QP1(hp0);   G1[1] = QP1(hp1);
        G0[2] = QP2(hp0);   G1[2] = QP2(hp1);
        G0[3] = QP2(G0[1]); G1[3] = QP2(G1[1]);
        G0[7] = RHM(hp0);   G1[7] = RHM(hp1);
        G0[6] = RHM(G0[1]); G1[6] = RHM(G1[1]);
        G0[5] = RHM(G0[2]); G1[5] = RHM(G1[2]);
        G0[4] = RHM(G0[3]); G1[4] = RHM(G1[3]);

        // Pu~[d] = P~[d] - kt0*HP0[r^d] - kt1*HP1[r^d]
        float Pu[8];
#pragma unroll
        for (int d = 0; d < 8; ++d)
          Pu[d] = Pt[d] - kt0 * G0[d] - kt1 * G1[d];

        // V~[dl] = sum_c Pu~[c] * Fde[dl][c]  (all-local, tree-summed)
        float V[8];
#pragma unroll
        for (int dl = 0; dl < 8; ++dl) {
          float u0 = fmaf(Pu[1], Fde[dl][1], Pu[0] * Fde[dl][0]);
          float u1 = fmaf(Pu[3], Fde[dl][3], Pu[2] * Fde[dl][2]);
          float u2 = fmaf(Pu[5], Fde[dl][5], Pu[4] * Fde[dl][4]);
          float u3 = fmaf(Pu[7], Fde[dl][7], Pu[6] * Fde[dl][6]);
          V[dl] = (u0 + u1) + (u2 + u3);
        }

        // Pn~[d] = Qt[d] + sum_e Frt[e] * (V~ @ lane r^e)[e^d]
        float Pn[8], A1[8], A2[8], A3[8], T[8];
#pragma unroll
        for (int d = 0; d < 8; ++d) Pn[d] = fmaf(Frt[0], V[d], Qt[d]);
#pragma unroll
        for (int c = 0; c < 8; ++c) A1[c] = QP1(V[c]);
#pragma unroll
        for (int d = 0; d < 8; ++d) Pn[d] = fmaf(Frt[1], A1[1 ^ d], Pn[d]);
#pragma unroll
        for (int c = 0; c < 8; ++c) A2[c] = QP2(V[c]);
#pragma unroll
        for (int d = 0; d < 8; ++d) Pn[d] = fmaf(Frt[2], A2[2 ^ d], Pn[d]);
#pragma unroll
        for (int c = 0; c < 8; ++c) A3[c] = QP2(A1[c]);
#pragma unroll
        for (int d = 0; d < 8; ++d) Pn[d] = fmaf(Frt[3], A3[3 ^ d], Pn[d]);
#pragma unroll
        for (int c = 0; c < 8; ++c) T[c] = RHM(V[c]);
#pragma unroll
        for (int d = 0; d < 8; ++d) Pn[d] = fmaf(Frt[7], T[7 ^ d], Pn[d]);
#pragma unroll
        for (int c = 0; c < 8; ++c) T[c] = RHM(A1[c]);
#pragma unroll
        for (int d = 0; d < 8; ++d) Pn[d] = fmaf(Frt[6], T[6 ^ d], Pn[d]);
#pragma unroll
        for (int c = 0; c < 8; ++c) T[c] = RHM(A2[c]);
#pragma unroll
        for (int d = 0; d < 8; ++d) Pn[d] = fmaf(Frt[5], T[5 ^ d], Pn[d]);
#pragma unroll
        for (int c = 0; c < 8; ++c) T[c] = RHM(A3[c]);
#pragma unroll
        for (int d = 0; d < 8; ++d) Pn[d] = fmaf(Frt[4], T[4 ^ d], Pn[d]);

        // freeze check vs pre-update P~ (every 2nd step)
        if (t & 1) {
          float dmax = 0.f;
#pragma unroll
          for (int c = 0; c < 8; ++c) dmax = fmaxf(dmax, fabsf(Pn[c] - Pt[c]));
          frozen = allmax8(dmax) < FREEZE_EPS;
        }
#pragma unroll
        for (int c = 0; c < 8; ++c) Pt[c] = Pn[c];
      }

      // ---- outputs (pre-update), split across lanes 0/1 ----
      if (r == 0) *reinterpret_cast<float2*>(mo + 2 * t) = make_float2(mm0, mm1);
      if (r == 1) *reinterpret_cast<float4*>(co + 4 * t) = make_float4(s00, s01, s01, s11);

      // ---- mean measurement+time update (all DPP) ----
      const float y0 = xt.x - mm0, y1 = xt.y - mm1;
      const float mu = fmaf(kt0, y0, fmaf(kt1, y1, m));
      m = matvec8(Fd, mu);

      // refill prefetch slot (8 steps ahead, clamped)
      int tf = tb + 8 + j; if (tf >= NT) tf = NT - 1;
      q[j] = *reinterpret_cast<const float2*>(xg + 2 * tf);
    }
  }
}

extern "C" void kernel_launch(void* const* d_in, const int* in_sizes, int n_in,
                              void* d_out, int out_size, void* d_ws, size_t ws_size,
                              hipStream_t stream) {
  const float* x  = (const float*)d_in[0];
  const float* m0 = (const float*)d_in[1];
  const float* P0 = (const float*)d_in[2];
  const float* F  = (const float*)d_in[3];
  const float* Q  = (const float*)d_in[4];
  const float* H  = (const float*)d_in[5];
  const float* R  = (const float*)d_in[6];
  float* out = (float*)d_out;

  dim3 grid(NG * 8 / 256), block(256);
  hipLaunchKernelGGL(kf_kernel, grid, block, 0, stream,
                     x, m0, P0, F, Q, H, R, out);
}